// Round 10
// baseline (53.781 us; speedup 1.0000x reference)
//
#include <hip/hip_runtime.h>

#define KK 4
#define TT 100000
#define NCLS 100
#define NN 4096
#define MARGIN_F 0.2f
#define EPS_F 1e-8f

#define NXCD 8
#define BPK 782                       // blocks per (k, xcd-slot); 782*2*4 waves = 6256 >= 6250 batches
#define NBLOCKS (BPK * NXCD)          // 6256
#define BATCHES_K 6250                // 6250 * 16 = 100000 triplets per k, exact
#define NCOPY 64
#define ACC_FLOATS (NCOPY * 16)
#define ACC_BYTES (ACC_FLOATS * 4)    // 4 KB
#define HB_BYTES (NN * KK * 128 * 2)  // fp16 batch, 4 MB

typedef _Float16 h2 __attribute__((ext_vector_type(2)));
typedef _Float16 f16x8 __attribute__((ext_vector_type(8)));
typedef float f32x4 __attribute__((ext_vector_type(4)));
struct H8 { h2 a, b, c, d; };         // 16 B = 8 halves

__device__ __forceinline__ float swz_add(float x, const int mask) {
    const int xi = __builtin_bit_cast(int, x);
    // mask is a compile-time literal at each call site below
    return x;
}

// fp32->fp16 convert + per-row |row|^2 (on quantized values) + {norm,beta} table + ws zero
__global__ __launch_bounds__(256) void prep(
    const float* __restrict__ src, const int* __restrict__ labels,
    const float* __restrict__ beta,
    _Float16* __restrict__ dst, float2* __restrict__ tbl, float* __restrict__ ws)
{
    const int i = blockIdx.x * blockDim.x + threadIdx.x;   // 0..262143
    const float4 v0 = ((const float4*)src)[i * 2];
    const float4 v1 = ((const float4*)src)[i * 2 + 1];
    H8 o;
    o.a = h2{(_Float16)v0.x, (_Float16)v0.y};
    o.b = h2{(_Float16)v0.z, (_Float16)v0.w};
    o.c = h2{(_Float16)v1.x, (_Float16)v1.y};
    o.d = h2{(_Float16)v1.z, (_Float16)v1.w};
    ((H8*)dst)[i] = o;

    // per-row squared norm of the QUANTIZED row (16 threads per 128-elem row)
    float sq = 0.f;
    sq = __builtin_amdgcn_fdot2(o.a, o.a, sq, false);
    sq = __builtin_amdgcn_fdot2(o.b, o.b, sq, false);
    sq = __builtin_amdgcn_fdot2(o.c, o.c, sq, false);
    sq = __builtin_amdgcn_fdot2(o.d, o.d, sq, false);
    // butterfly over the 16 lanes of this row (xor 1,2,4,8)
    sq += __builtin_bit_cast(float, __builtin_amdgcn_ds_swizzle(__builtin_bit_cast(int, sq), 0x041F));
    sq += __builtin_bit_cast(float, __builtin_amdgcn_ds_swizzle(__builtin_bit_cast(int, sq), 0x081F));
    sq += __builtin_bit_cast(float, __builtin_amdgcn_ds_swizzle(__builtin_bit_cast(int, sq), 0x101F));
    sq += __builtin_bit_cast(float, __builtin_amdgcn_ds_swizzle(__builtin_bit_cast(int, sq), 0x201F));
    if ((i & 15) == 0) {
        const int r = i >> 4;                     // global row 0..16383 (= n*4+k)
        tbl[(r & 3) * NN + (r >> 2)].x = sq;      // norm
    }

    if (i < KK * NN) {                            // beta lookup: tbl[k][n].y = beta[k][labels[n]]
        const int n = i >> 2, k = i & 3;
        tbl[k * NN + n].y = beta[k * NCLS + labels[n]];
    }
    if (i < ACC_FLOATS) ws[i] = 0.f;
}

// ws layout: ws[c*16 + j], j<4: totals, j in [4,8): counts
__global__ __launch_bounds__(256) void margin_main(
    const _Float16* __restrict__ hb,
    const int* __restrict__ triplets,
    const float2* __restrict__ tbl,
    float* __restrict__ ws)
{
    __shared__ float s_red[8];
    const int tid  = threadIdx.x;
    const int lane = tid & 63;
    const int wave = tid >> 6;
    const int c    = lane & 15;       // triplet column within the 16-batch
    const int h    = lane >> 4;       // k-chunk sub-index (0..3)

    // XCD-pinned k
    const int xcd      = blockIdx.x & (NXCD - 1);
    const int k        = xcd >> 1;                                  // 0..3
    const int blk_in_k = (xcd & 1) * BPK + (blockIdx.x >> 3);       // 0..1563

    const int batch  = blk_in_k * 4 + wave;       // 0..6255
    const bool bvalid = (batch < BATCHES_K);
    const int t = bvalid ? (batch * 16 + c) : c;  // 16 triplets per wave-batch

    const int* tp = triplets + (k * TT + t) * 3;
    const int i0 = tp[0];
    const int i1 = tp[1];
    const int i2 = tp[2];

    // fragment bases: row = 128 halves = 16 x f16x8; chunk cc uses index cc*4 + h
    const f16x8* __restrict__ ra = (const f16x8*)(hb + (((long long)(i0 << 2) + k) << 7));
    const f16x8* __restrict__ rp = (const f16x8*)(hb + (((long long)(i1 << 2) + k) << 7));
    const f16x8* __restrict__ rn = (const f16x8*)(hb + (((long long)(i2 << 2) + k) << 7));

    // issue all 12 fragment loads + 3 table loads before compute
    const f16x8 a0 = ra[h],      a1 = ra[4 + h], a2 = ra[8 + h], a3 = ra[12 + h];
    const f16x8 p0 = rp[h],      p1 = rp[4 + h], p2 = rp[8 + h], p3 = rp[12 + h];
    const f16x8 n0 = rn[h],      n1 = rn[4 + h], n2 = rn[8 + h], n3 = rn[12 + h];
    const float2* __restrict__ tbl_k = tbl + k * NN;
    const float2 ta = tbl_k[i0];   // {norm_a, beta}
    const float2 tq = tbl_k[i1];   // {norm_p, -}
    const float2 tn = tbl_k[i2];   // {norm_n, -}
    __builtin_amdgcn_sched_barrier(0);

    f32x4 acc_p = {0.f, 0.f, 0.f, 0.f};
    f32x4 acc_n = {0.f, 0.f, 0.f, 0.f};
    acc_p = __builtin_amdgcn_mfma_f32_16x16x32_f16(a0, p0, acc_p, 0, 0, 0);
    acc_n = __builtin_amdgcn_mfma_f32_16x16x32_f16(a0, n0, acc_n, 0, 0, 0);
    acc_p = __builtin_amdgcn_mfma_f32_16x16x32_f16(a1, p1, acc_p, 0, 0, 0);
    acc_n = __builtin_amdgcn_mfma_f32_16x16x32_f16(a1, n1, acc_n, 0, 0, 0);
    acc_p = __builtin_amdgcn_mfma_f32_16x16x32_f16(a2, p2, acc_p, 0, 0, 0);
    acc_n = __builtin_amdgcn_mfma_f32_16x16x32_f16(a2, n2, acc_n, 0, 0, 0);
    acc_p = __builtin_amdgcn_mfma_f32_16x16x32_f16(a3, p3, acc_p, 0, 0, 0);
    acc_n = __builtin_amdgcn_mfma_f32_16x16x32_f16(a3, n3, acc_n, 0, 0, 0);

    // diagonal lives on lanes where h == c>>2, at reg jj = c&3
    const bool isdiag = (h == (c >> 2));
    const int jj = c & 3;
    const float p01 = (jj & 1) ? acc_p[1] : acc_p[0];
    const float p23 = (jj & 1) ? acc_p[3] : acc_p[2];
    const float dp  = (jj & 2) ? p23 : p01;
    const float q01 = (jj & 1) ? acc_n[1] : acc_n[0];
    const float q23 = (jj & 1) ? acc_n[3] : acc_n[2];
    const float dn  = (jj & 2) ? q23 : q01;

    const float dsq_p = fmaxf(ta.x + tq.x - 2.f * dp, 0.f);
    const float dsq_n = fmaxf(ta.x + tn.x - 2.f * dn, 0.f);
    const float d_ap = sqrtf(dsq_p + EPS_F);
    const float d_an = sqrtf(dsq_n + EPS_F);
    const float b = ta.y;
    const float pl = fmaxf(d_ap - b + MARGIN_F, 0.f);
    const float nl = fmaxf(b - d_an + MARGIN_F, 0.f);

    const bool act = isdiag && bvalid;
    float lt = act ? (pl + nl) : 0.f;
    float lc = (act && (pl > 0.f || nl > 0.f)) ? 1.f : 0.f;

    // wave reduce (16 active lanes -> lane 0)
    #pragma unroll
    for (int o = 1; o <= 32; o <<= 1) {
        lt += __shfl_xor(lt, o);
        lc += __shfl_xor(lc, o);
    }
    if (lane == 0) { s_red[wave] = lt; s_red[4 + wave] = lc; }
    __syncthreads();

    if (tid == 0) {
        const float tot = s_red[0] + s_red[1] + s_red[2] + s_red[3];
        const float cnt = s_red[4] + s_red[5] + s_red[6] + s_red[7];
        const int cc = (blockIdx.x >> 3) & (NCOPY - 1);
        atomicAdd(&ws[cc * 16 + k], tot);
        atomicAdd(&ws[cc * 16 + 4 + k], cnt);
    }
}

__global__ void margin_final(const float* __restrict__ ws, float* __restrict__ out) {
    if (threadIdx.x == 0 && blockIdx.x == 0) {
        float acc = 0.f;
        #pragma unroll
        for (int k = 0; k < KK; ++k) {
            float tot = 0.f, cnt = 0.f;
            for (int c = 0; c < NCOPY; ++c) {
                tot += ws[c * 16 + k];
                cnt += ws[c * 16 + 4 + k];
            }
            const float lk = (cnt == 0.f) ? tot : tot / fmaxf(cnt, 1.f);
            acc += lk;
        }
        out[0] = acc / (float)KK;
    }
}

extern "C" void kernel_launch(void* const* d_in, const int* in_sizes, int n_in,
                              void* d_out, int out_size, void* d_ws, size_t ws_size,
                              hipStream_t stream) {
    const float* batch    = (const float*)d_in[0];
    const int*   labels   = (const int*)d_in[1];
    const int*   triplets = (const int*)d_in[2];
    const float* beta     = (const float*)d_in[3];

    float*     ws  = (float*)d_ws;
    _Float16*  hb  = (_Float16*)((char*)d_ws + ACC_BYTES);
    float2*    tbl = (float2*)((char*)d_ws + ACC_BYTES + HB_BYTES);

    prep<<<1024, 256, 0, stream>>>(batch, labels, beta, hb, tbl, ws);
    margin_main<<<NBLOCKS, 256, 0, stream>>>(hb, triplets, tbl, ws);
    margin_final<<<1, 64, 0, stream>>>(ws, (float*)d_out);
}

// Round 11
// 53.161 us; speedup vs baseline: 1.0117x; 1.0117x over previous
//
#include <hip/hip_runtime.h>

#define KK 4
#define TT 100000
#define NCLS 100
#define NN 4096
#define MARGIN_F 0.2f
#define EPS_F 1e-8f

#define NXCD 8
#define BPK 782                       // blocks per (k, xcd-slot); 782*2*4 waves = 6256 >= 6250 batches
#define NBLOCKS (BPK * NXCD)          // 6256
#define BATCHES_K 6250                // 6250 * 16 = 100000 triplets per k, exact
#define NCOPY 64
#define ACC_FLOATS (NCOPY * 16)
#define ACC_BYTES (ACC_FLOATS * 4)    // 4 KB
#define HB_BYTES (NN * KK * 128)      // fp8 batch, 2 MB (row = 128 B = 1 line)

typedef float f32x4 __attribute__((ext_vector_type(4)));
typedef float f32x2 __attribute__((ext_vector_type(2)));

// fp32->fp8(e4m3) convert + per-row |row|^2 on QUANTIZED values + {norm,beta} table + ws zero
__global__ __launch_bounds__(256) void prep(
    const float* __restrict__ src, const int* __restrict__ labels,
    const float* __restrict__ beta,
    uint2* __restrict__ dst, float2* __restrict__ tbl, float* __restrict__ ws)
{
    const int i = blockIdx.x * blockDim.x + threadIdx.x;   // 0..262143, 8 floats each
    const float4 v0 = ((const float4*)src)[i * 2];
    const float4 v1 = ((const float4*)src)[i * 2 + 1];

    int lo = 0, hi = 0;
    lo = __builtin_amdgcn_cvt_pk_fp8_f32(v0.x, v0.y, lo, false);
    lo = __builtin_amdgcn_cvt_pk_fp8_f32(v0.z, v0.w, lo, true);
    hi = __builtin_amdgcn_cvt_pk_fp8_f32(v1.x, v1.y, hi, false);
    hi = __builtin_amdgcn_cvt_pk_fp8_f32(v1.z, v1.w, hi, true);
    dst[i] = uint2{(unsigned)lo, (unsigned)hi};

    // dequantize and accumulate |row|^2 partial (8 values)
    const f32x2 d0 = __builtin_amdgcn_cvt_pk_f32_fp8(lo, false);
    const f32x2 d1 = __builtin_amdgcn_cvt_pk_f32_fp8(lo, true);
    const f32x2 d2 = __builtin_amdgcn_cvt_pk_f32_fp8(hi, false);
    const f32x2 d3 = __builtin_amdgcn_cvt_pk_f32_fp8(hi, true);
    float sq = d0.x * d0.x + d0.y * d0.y + d1.x * d1.x + d1.y * d1.y
             + d2.x * d2.x + d2.y * d2.y + d3.x * d3.x + d3.y * d3.y;

    // butterfly over the 16 lanes of this row (xor 1,2,4,8)
    sq += __builtin_bit_cast(float, __builtin_amdgcn_ds_swizzle(__builtin_bit_cast(int, sq), 0x041F));
    sq += __builtin_bit_cast(float, __builtin_amdgcn_ds_swizzle(__builtin_bit_cast(int, sq), 0x081F));
    sq += __builtin_bit_cast(float, __builtin_amdgcn_ds_swizzle(__builtin_bit_cast(int, sq), 0x101F));
    sq += __builtin_bit_cast(float, __builtin_amdgcn_ds_swizzle(__builtin_bit_cast(int, sq), 0x201F));
    if ((i & 15) == 0) {
        const int r = i >> 4;                     // global row (= n*4+k)
        tbl[(r & 3) * NN + (r >> 2)].x = sq;      // norm
    }

    if (i < KK * NN) {                            // tbl[k][n].y = beta[k][labels[n]]
        const int n = i >> 2, k = i & 3;
        tbl[k * NN + n].y = beta[k * NCLS + labels[n]];
    }
    if (i < ACC_FLOATS) ws[i] = 0.f;
}

// ws layout: ws[c*16 + j], j<4: totals, j in [4,8): counts
__global__ __launch_bounds__(256) void margin_main(
    const unsigned char* __restrict__ hb,
    const int* __restrict__ triplets,
    const float2* __restrict__ tbl,
    float* __restrict__ ws)
{
    __shared__ float s_red[8];
    const int tid  = threadIdx.x;
    const int lane = tid & 63;
    const int wave = tid >> 6;
    const int c    = lane & 15;       // triplet column within the 16-batch
    const int h    = lane >> 4;       // K-subchunk index (0..3): 8 fp8 at m*32 + h*8

    // XCD-pinned k
    const int xcd      = blockIdx.x & (NXCD - 1);
    const int k        = xcd >> 1;                                  // 0..3
    const int blk_in_k = (xcd & 1) * BPK + (blockIdx.x >> 3);       // 0..1563

    const int batch   = blk_in_k * 4 + wave;      // 0..6255
    const bool bvalid = (batch < BATCHES_K);
    const int t = bvalid ? (batch * 16 + c) : c;  // 16 triplets per wave

    const int* tp = triplets + (k * TT + t) * 3;
    const int i0 = tp[0];
    const int i1 = tp[1];
    const int i2 = tp[2];

    // fp8 row base: row (n*4+k) * 128 bytes
    const unsigned char* ra = hb + (((long long)(i0 << 2) + k) << 7);
    const unsigned char* rp = hb + (((long long)(i1 << 2) + k) << 7);
    const unsigned char* rn = hb + (((long long)(i2 << 2) + k) << 7);
    const int ho = h * 8;

    // issue all 12 fragment loads (8 B each) + 3 table loads before compute
    const long a0 = *(const long*)(ra + ho);
    const long a1 = *(const long*)(ra + 32 + ho);
    const long a2 = *(const long*)(ra + 64 + ho);
    const long a3 = *(const long*)(ra + 96 + ho);
    const long p0 = *(const long*)(rp + ho);
    const long p1 = *(const long*)(rp + 32 + ho);
    const long p2 = *(const long*)(rp + 64 + ho);
    const long p3 = *(const long*)(rp + 96 + ho);
    const long n0 = *(const long*)(rn + ho);
    const long n1 = *(const long*)(rn + 32 + ho);
    const long n2 = *(const long*)(rn + 64 + ho);
    const long n3 = *(const long*)(rn + 96 + ho);
    const float2* tbl_k = tbl + k * NN;
    const float2 ta = tbl_k[i0];   // {norm_a, beta}
    const float2 tq = tbl_k[i1];   // {norm_p, -}
    const float2 tn = tbl_k[i2];   // {norm_n, -}
    __builtin_amdgcn_sched_barrier(0);

    f32x4 acc_p = {0.f, 0.f, 0.f, 0.f};
    f32x4 acc_n = {0.f, 0.f, 0.f, 0.f};
    acc_p = __builtin_amdgcn_mfma_f32_16x16x32_fp8_fp8(a0, p0, acc_p, 0, 0, 0);
    acc_n = __builtin_amdgcn_mfma_f32_16x16x32_fp8_fp8(a0, n0, acc_n, 0, 0, 0);
    acc_p = __builtin_amdgcn_mfma_f32_16x16x32_fp8_fp8(a1, p1, acc_p, 0, 0, 0);
    acc_n = __builtin_amdgcn_mfma_f32_16x16x32_fp8_fp8(a1, n1, acc_n, 0, 0, 0);
    acc_p = __builtin_amdgcn_mfma_f32_16x16x32_fp8_fp8(a2, p2, acc_p, 0, 0, 0);
    acc_n = __builtin_amdgcn_mfma_f32_16x16x32_fp8_fp8(a2, n2, acc_n, 0, 0, 0);
    acc_p = __builtin_amdgcn_mfma_f32_16x16x32_fp8_fp8(a3, p3, acc_p, 0, 0, 0);
    acc_n = __builtin_amdgcn_mfma_f32_16x16x32_fp8_fp8(a3, n3, acc_n, 0, 0, 0);

    // diagonal D[c][c] lives on lanes where h == c>>2, at reg jj = c&3
    const bool isdiag = (h == (c >> 2));
    const int jj = c & 3;
    const float p01 = (jj & 1) ? acc_p[1] : acc_p[0];
    const float p23 = (jj & 1) ? acc_p[3] : acc_p[2];
    const float dp  = (jj & 2) ? p23 : p01;
    const float q01 = (jj & 1) ? acc_n[1] : acc_n[0];
    const float q23 = (jj & 1) ? acc_n[3] : acc_n[2];
    const float dn  = (jj & 2) ? q23 : q01;

    const float dsq_p = fmaxf(ta.x + tq.x - 2.f * dp, 0.f);
    const float dsq_n = fmaxf(ta.x + tn.x - 2.f * dn, 0.f);
    const float d_ap = sqrtf(dsq_p + EPS_F);
    const float d_an = sqrtf(dsq_n + EPS_F);
    const float b = ta.y;
    const float pl = fmaxf(d_ap - b + MARGIN_F, 0.f);
    const float nl = fmaxf(b - d_an + MARGIN_F, 0.f);

    const bool act = isdiag && bvalid;
    float lt = act ? (pl + nl) : 0.f;
    float lc = (act && (pl > 0.f || nl > 0.f)) ? 1.f : 0.f;

    // wave reduce (16 active lanes -> lane 0)
    #pragma unroll
    for (int o = 1; o <= 32; o <<= 1) {
        lt += __shfl_xor(lt, o);
        lc += __shfl_xor(lc, o);
    }
    if (lane == 0) { s_red[wave] = lt; s_red[4 + wave] = lc; }
    __syncthreads();

    if (tid == 0) {
        const float tot = s_red[0] + s_red[1] + s_red[2] + s_red[3];
        const float cnt = s_red[4] + s_red[5] + s_red[6] + s_red[7];
        const int cc = (blockIdx.x >> 3) & (NCOPY - 1);
        atomicAdd(&ws[cc * 16 + k], tot);
        atomicAdd(&ws[cc * 16 + 4 + k], cnt);
    }
}

__global__ void margin_final(const float* __restrict__ ws, float* __restrict__ out) {
    if (threadIdx.x == 0 && blockIdx.x == 0) {
        float acc = 0.f;
        #pragma unroll
        for (int k = 0; k < KK; ++k) {
            float tot = 0.f, cnt = 0.f;
            for (int c = 0; c < NCOPY; ++c) {
                tot += ws[c * 16 + k];
                cnt += ws[c * 16 + 4 + k];
            }
            const float lk = (cnt == 0.f) ? tot : tot / fmaxf(cnt, 1.f);
            acc += lk;
        }
        out[0] = acc / (float)KK;
    }
}

extern "C" void kernel_launch(void* const* d_in, const int* in_sizes, int n_in,
                              void* d_out, int out_size, void* d_ws, size_t ws_size,
                              hipStream_t stream) {
    const float* batch    = (const float*)d_in[0];
    const int*   labels   = (const int*)d_in[1];
    const int*   triplets = (const int*)d_in[2];
    const float* beta     = (const float*)d_in[3];

    float*          ws  = (float*)d_ws;
    uint2*          hb2 = (uint2*)((char*)d_ws + ACC_BYTES);
    unsigned char*  hb  = (unsigned char*)hb2;
    float2*         tbl = (float2*)((char*)d_ws + ACC_BYTES + HB_BYTES);

    prep<<<1024, 256, 0, stream>>>(batch, labels, beta, hb2, tbl, ws);
    margin_main<<<NBLOCKS, 256, 0, stream>>>(hb, triplets, tbl, ws);
    margin_final<<<1, 64, 0, stream>>>(ws, (float*)d_out);
}